// Round 5
// baseline (439.196 us; speedup 1.0000x reference)
//
#include <hip/hip_runtime.h>
#include <hip/hip_bf16.h>
#include <math.h>

// Problem constants
#define BS 32
#define TT 512
#define HH 1024
#define NH 16
#define DH 64
#define MM (BS*TT)          // 16384 rows
#define NCAT 2176           // 1024(Q) + 1024(K) + 64(V) + 64(pad)

typedef __attribute__((ext_vector_type(8))) __bf16 bf16x8;
typedef __attribute__((ext_vector_type(4))) float  f32x4;

#define QSCALE 0.18033688011112042f   // dh^-0.5 * log2(e) -> softmax in exp2 domain

// Native 2^x (single v_exp_f32). Without fast-math, plain exp2f expands to a
// ~25-op precise VALU sequence: R4 counters showed ~594 VALU cyc/iter, ~450
// of which match 16 such expansions -> this was the serial-chain bottleneck.
#if __has_builtin(__builtin_amdgcn_exp2f)
#define EXP2F(x) __builtin_amdgcn_exp2f(x)
#else
#define EXP2F(x) __expf((x) * 0.69314718055994531f)
#endif

// async global->LDS, 16B per lane, LDS dest = wave-uniform base + lane*16
__device__ __forceinline__ void gld16(const void* g, void* l) {
    __builtin_amdgcn_global_load_lds(
        (const __attribute__((address_space(1))) unsigned int*)g,
        (__attribute__((address_space(3))) unsigned int*)l,
        16, 0, 0);
}

// ---------------------------------------------------------------------------
// Prep 1: x fp32 -> bf16 (row-major [M][K] unchanged)
// ---------------------------------------------------------------------------
__global__ __launch_bounds__(256) void cvt_x(const float* __restrict__ x,
                                             __bf16* __restrict__ xb)
{
    const size_t i = ((size_t)blockIdx.x * 256 + threadIdx.x) * 8;
    float4 a = *(const float4*)(x + i);
    float4 b = *(const float4*)(x + i + 4);
    bf16x8 v;
    v[0] = (__bf16)a.x; v[1] = (__bf16)a.y; v[2] = (__bf16)a.z; v[3] = (__bf16)a.w;
    v[4] = (__bf16)b.x; v[5] = (__bf16)b.y; v[6] = (__bf16)b.z; v[7] = (__bf16)b.w;
    *(bf16x8*)(xb + i) = v;
}

// ---------------------------------------------------------------------------
// Prep 2: Wt[n][k] bf16 = concat(Wq,Wk,Wv,0)^T; bias_cat[n] fp32.
// ---------------------------------------------------------------------------
__global__ __launch_bounds__(256) void prep_w(
    const float* __restrict__ Wq, const float* __restrict__ Wk,
    const float* __restrict__ Wv, const float* __restrict__ bq_,
    const float* __restrict__ bk_, const float* __restrict__ bv_,
    __bf16* __restrict__ Wt, float* __restrict__ bias_cat)
{
    __shared__ __align__(16) __bf16 tile[64][72];
    const int tid = threadIdx.x;
    const int n0 = blockIdx.x * 64;
    const int k0 = blockIdx.y * 64;

    const int n_l = tid & 63;
    const int k_b = tid >> 6;
    const int n   = n0 + n_l;
    #pragma unroll
    for (int j = 0; j < 16; ++j) {
        const int k_l = j * 4 + k_b;
        const int k   = k0 + k_l;
        float v;
        if (n < 1024)      v = Wq[(size_t)k * 1024 + n];
        else if (n < 2048) v = Wk[(size_t)k * 1024 + (n - 1024)];
        else if (n < 2112) v = Wv[(size_t)k * 64 + (n - 2048)];
        else               v = 0.f;
        tile[n_l][k_l] = (__bf16)v;
    }
    if (blockIdx.y == 0 && tid < 64) {
        const int nn = n0 + tid;
        bias_cat[nn] = (nn < 1024) ? bq_[nn]
                     : (nn < 2048) ? bk_[nn - 1024]
                     : (nn < 2112) ? bv_[nn - 2048] : 0.f;
    }
    __syncthreads();
    const int n_l2 = tid >> 2;
    const int k_l2 = (tid & 3) * 16;
    __bf16* dst = Wt + (size_t)(n0 + n_l2) * 1024 + k0 + k_l2;
    *(bf16x8*)dst       = *(const bf16x8*)&tile[n_l2][k_l2];
    *(bf16x8*)(dst + 8) = *(const bf16x8*)&tile[n_l2][k_l2 + 8];
}

// ---------------------------------------------------------------------------
// Fused QKV GEMM, m97 structure: 128x128 tile, BK=32, global_load_lds w=16.
// Bijective XCD-aware block swizzle (nwg=2176=8*272) for L2 locality.
// ---------------------------------------------------------------------------
__global__ __launch_bounds__(256) void gemm_qkv(
    const __bf16* __restrict__ A, const __bf16* __restrict__ B,
    const float* __restrict__ bias_cat,
    __bf16* __restrict__ Qo, __bf16* __restrict__ Ko,
    __bf16* __restrict__ Vt)
{
    __shared__ __align__(16) __bf16 sA[128 * 32];
    __shared__ __align__(16) __bf16 sB[128 * 32];

    const int tid  = threadIdx.x;
    const int wv   = tid >> 6;
    const int ln   = tid & 63;
    const int quad = ln >> 4;
    const int l16  = ln & 15;

    // XCD swizzle: grid = dim3(17,128) -> 2176 blocks, 2176 % 8 == 0
    const int orig = blockIdx.y * 17 + blockIdx.x;
    const int swz  = (orig & 7) * 272 + (orig >> 3);
    const int m0 = (swz / 17) * 128;
    const int n0 = (swz % 17) * 128;

    const int rw = (wv & 1) * 64;    // wave row quadrant
    const int cw = (wv >> 1) * 64;   // wave col quadrant

    f32x4 acc[4][4];
    #pragma unroll
    for (int i = 0; i < 4; ++i)
        #pragma unroll
        for (int j = 0; j < 4; ++j) acc[i][j] = f32x4{0, 0, 0, 0};

    const int srow = wv * 16 + (ln >> 2);
    const int scol = (ln & 3) * 8;
    const __bf16* ga0 = A + (size_t)(m0 + srow) * 1024 + scol;
    const __bf16* gb0 = B + (size_t)(n0 + srow) * 1024 + scol;
    __bf16* la0 = sA + wv * 512;
    __bf16* lb0 = sB + wv * 512;

    for (int k0 = 0; k0 < 1024; k0 += 32) {
        gld16(ga0 + k0, la0);
        gld16(ga0 + (size_t)64 * 1024 + k0, la0 + 2048);
        gld16(gb0 + k0, lb0);
        gld16(gb0 + (size_t)64 * 1024 + k0, lb0 + 2048);
        __syncthreads();

        bf16x8 af[4], bfr[4];
        #pragma unroll
        for (int mt = 0; mt < 4; ++mt)
            af[mt] = *(const bf16x8*)&sA[(rw + mt * 16 + l16) * 32 + quad * 8];
        #pragma unroll
        for (int nt = 0; nt < 4; ++nt)
            bfr[nt] = *(const bf16x8*)&sB[(cw + nt * 16 + l16) * 32 + quad * 8];
        #pragma unroll
        for (int mt = 0; mt < 4; ++mt)
            #pragma unroll
            for (int nt = 0; nt < 4; ++nt)
                acc[mt][nt] = __builtin_amdgcn_mfma_f32_16x16x32_bf16(af[mt], bfr[nt], acc[mt][nt], 0, 0, 0);
        __syncthreads();
    }

    #pragma unroll
    for (int mt = 0; mt < 4; ++mt) {
        #pragma unroll
        for (int nt = 0; nt < 4; ++nt) {
            const int colb = n0 + cw + nt * 16 + l16;
            if (colb >= 2112) continue;
            const float bias = bias_cat[colb];
            #pragma unroll
            for (int r = 0; r < 4; ++r) {
                const int row = m0 + rw + mt * 16 + quad * 4 + r;
                const int b = row >> 9, t = row & 511;
                float v = acc[mt][nt][r] + bias;
                if (colb < 1024) {
                    const int h = colb >> 6, d = colb & 63;
                    Qo[(((size_t)(b * NH + h) * TT) + t) * DH + d] = (__bf16)(v * QSCALE);
                } else if (colb < 2048) {
                    const int c = colb - 1024;
                    const int h = c >> 6, d = c & 63;
                    Ko[(((size_t)(b * NH + h) * TT) + t) * DH + d] = (__bf16)v;
                } else {
                    const int d = colb - 2048;
                    Vt[((size_t)(b * DH + d)) * TT + t] = (__bf16)v;
                }
            }
        }
    }
}

// ---------------------------------------------------------------------------
// MFMA flash attention, v5.
// R4 counters: FETCH collapsed (K is an L2 hit) but time flat -> NOT memory.
// VALUBusy 18.6% = ~594 VALU cyc per wave-iteration vs ~150 visible in source:
// exp2f without fast-math expands to a ~25-op precise VALU sequence (16/iter)
// -> the dominant per-iteration serial chain. Fixes:
//  * EXP2F: native v_exp_f32 (one op).
//  * constant-sum CU pairing: blocks i and i+256 land on the same CU slot
//    (same XCD: 256%8==0, same ring position); map so qt2(i)+qt2(i+256)=15
//    -> every CU runs exactly 17 wave-iterations per wave pair (was 10..24,
//    a 2.4x CU imbalance that set the kernel tail).
//  * T5 setprio around the MFMA clusters (attn-positive, m191).
//  * smav re-padded to pitch 65 (conflict-free epilogue LDS atomics).
// Block = (b,qt2): 16 waves = 16 heads, one 32-query tile; V staged once
// (XOR-swizzled, T21-compliant); K 2-deep register pipeline (L2-resident).
// ---------------------------------------------------------------------------
__global__ __launch_bounds__(1024) void attn_mfma(
    const __bf16* __restrict__ Q, const __bf16* __restrict__ K,
    const __bf16* __restrict__ Vt, float* __restrict__ attn_vec,
    float* __restrict__ mav)
{
    __shared__ __align__(16) __bf16 sV[64][512];   // 64 KB, XOR-swizzled col groups
    __shared__ float smav[32][65];                 // 8.3 KB, +1 pad: conflict-free atomics

    const int bid  = blockIdx.x;
    // constant-sum pairing: bid<256 -> qt2 = 15-(bid>>5) in {15..8};
    //                       bid>=256 -> qt2 = (bid-256)>>5 in {0..7}.
    const int qt2  = (bid < 256) ? (15 - (bid >> 5)) : ((bid - 256) >> 5);
    const int b    = bid & 31;             // bid%8 == b%8 -> same-b -> same XCD
    const int wave = threadIdx.x >> 6;     // = head
    const int lane = threadIdx.x & 63;
    const int quad = lane >> 4;
    const int l16  = lane & 15;
    const int bh   = b * NH + wave;
    const int q0   = qt2 << 5;
    const int kend = q0 + 32;

    // zero the LDS head-mean accumulator (32x65 = 2080 floats)
    {
        float* p = &smav[0][0];
        p[threadIdx.x] = 0.f;
        p[threadIdx.x + 1024] = 0.f;
        if (threadIdx.x < 32) p[threadIdx.x + 2048] = 0.f;
    }

    // stage V swizzled: wave w stages rows w, w+16, w+32, w+48 (full rows).
    // LDS dest linear (group = lane); global source group = lane ^ (row&7).
    const __bf16* Vb = Vt + (size_t)b * DH * TT;
    const int svw = wave & 7;              // row&7 for all 4 staged rows
    #pragma unroll
    for (int r = 0; r < 4; ++r) {
        const int row = wave + r * 16;
        gld16(Vb + (size_t)row * TT + ((lane ^ svw) * 8), &sV[row][0]);
    }

    const __bf16* Qbh = Q + (size_t)bh * TT * DH;
    const __bf16* Kbh = K + (size_t)bh * TT * DH;

    // permuted K row: sigma1(l16) = (l16>>2)*8 + (l16&3); sigma2 = +4
    const int perm = ((l16 >> 2) << 3) + (l16 & 3);
    const __bf16* kp1 = Kbh + (size_t)perm * DH;
    const __bf16* kp2 = Kbh + (size_t)(perm + 4) * DH;

    // Q fragments for this wave's single 32-query tile
    const bf16x8 qA_lo = *(const bf16x8*)(Qbh + (size_t)(q0 + l16) * DH + quad * 8);
    const bf16x8 qA_hi = *(const bf16x8*)(Qbh + (size_t)(q0 + l16) * DH + 32 + quad * 8);
    const bf16x8 qB_lo = *(const bf16x8*)(Qbh + (size_t)(q0 + 16 + l16) * DH + quad * 8);
    const bf16x8 qB_hi = *(const bf16x8*)(Qbh + (size_t)(q0 + 16 + l16) * DH + 32 + quad * 8);

    f32x4 OA[4] = {f32x4{0,0,0,0}, f32x4{0,0,0,0}, f32x4{0,0,0,0}, f32x4{0,0,0,0}};
    f32x4 OB[4] = {f32x4{0,0,0,0}, f32x4{0,0,0,0}, f32x4{0,0,0,0}, f32x4{0,0,0,0}};
    float lA = 0.f, lB = 0.f;     // per-lane partial denominators

    // 2-deep K register pipeline: cur (c*) + next (n*)
    bf16x8 c1a = *(const bf16x8*)(kp1 + quad * 8);
    bf16x8 c1b = *(const bf16x8*)(kp1 + 32 + quad * 8);
    bf16x8 c2a = *(const bf16x8*)(kp2 + quad * 8);
    bf16x8 c2b = *(const bf16x8*)(kp2 + 32 + quad * 8);
    const int kb1 = (32 < kend) ? 32 : 0;
    bf16x8 n1a = *(const bf16x8*)(kp1 + (size_t)kb1 * DH + quad * 8);
    bf16x8 n1b = *(const bf16x8*)(kp1 + (size_t)kb1 * DH + 32 + quad * 8);
    bf16x8 n2a = *(const bf16x8*)(kp2 + (size_t)kb1 * DH + quad * 8);
    bf16x8 n2b = *(const bf16x8*)(kp2 + (size_t)kb1 * DH + 32 + quad * 8);

    const int sx = l16 & 7;       // V read swizzle (row&7 of all 4 V rows)

    __syncthreads();   // V staged (compiler drains vmcnt before s_barrier)

    for (int kb0 = 0; kb0 < kend; kb0 += 32) {
        // V fragments from LDS, swizzled read: group gd=(kb0>>3)+quad -> gd^sx
        const int vg = (((kb0 >> 3) + quad) ^ sx) * 8;
        bf16x8 vf0 = *(const bf16x8*)&sV[l16][vg];
        bf16x8 vf1 = *(const bf16x8*)&sV[16 + l16][vg];
        bf16x8 vf2 = *(const bf16x8*)&sV[32 + l16][vg];
        bf16x8 vf3 = *(const bf16x8*)&sV[48 + l16][vg];

        __builtin_amdgcn_s_setprio(1);
        f32x4 s1A = __builtin_amdgcn_mfma_f32_16x16x32_bf16(c1a, qA_lo, f32x4{0,0,0,0}, 0, 0, 0);
        s1A       = __builtin_amdgcn_mfma_f32_16x16x32_bf16(c1b, qA_hi, s1A, 0, 0, 0);
        f32x4 s2A = __builtin_amdgcn_mfma_f32_16x16x32_bf16(c2a, qA_lo, f32x4{0,0,0,0}, 0, 0, 0);
        s2A       = __builtin_amdgcn_mfma_f32_16x16x32_bf16(c2b, qA_hi, s2A, 0, 0, 0);
        f32x4 s1B = __builtin_amdgcn_mfma_f32_16x16x32_bf16(c1a, qB_lo, f32x4{0,0,0,0}, 0, 0, 0);
        s1B       = __builtin_amdgcn_mfma_f32_16x16x32_bf16(c1b, qB_hi, s1B, 0, 0, 0);
        f32x4 s2B = __builtin_amdgcn_mfma_f32_16x16x32_bf16(c2a, qB_lo, f32x4{0,0,0,0}, 0, 0, 0);
        s2B       = __builtin_amdgcn_mfma_f32_16x16x32_bf16(c2b, qB_hi, s2B, 0, 0, 0);
        __builtin_amdgcn_s_setprio(0);

        if (kb0 == q0) {   // only the diagonal block needs masking
            const int qqA = q0 + l16, qqB = q0 + 16 + l16;
            #pragma unroll
            for (int r = 0; r < 4; ++r) {
                const int key1 = kb0 + quad * 8 + r;
                const int key2 = key1 + 4;
                if (key1 > qqA) s1A[r] = -INFINITY;
                if (key2 > qqA) s2A[r] = -INFINITY;
                if (key1 > qqB) s1B[r] = -INFINITY;
                if (key2 > qqB) s2B[r] = -INFINITY;
            }
        }

        // p = exp2(s) via native v_exp_f32; accumulate per-lane denominator
        bf16x8 pfA, pfB;
        float psA0 = 0.f, psA1 = 0.f, psB0 = 0.f, psB1 = 0.f;
        #pragma unroll
        for (int r = 0; r < 4; ++r) {
            float pa0 = EXP2F(s1A[r]);
            float pa1 = EXP2F(s2A[r]);
            float pb0 = EXP2F(s1B[r]);
            float pb1 = EXP2F(s2B[r]);
            psA0 += pa0; psA1 += pa1;
            psB0 += pb0; psB1 += pb1;
            pfA[r]     = (__bf16)pa0;
            pfA[4 + r] = (__bf16)pa1;
            pfB[r]     = (__bf16)pb0;
            pfB[4 + r] = (__bf16)pb1;
        }
        lA += psA0 + psA1;
        lB += psB0 + psB1;

        __builtin_amdgcn_s_setprio(1);
        OA[0] = __builtin_amdgcn_mfma_f32_16x16x32_bf16(pfA, vf0, OA[0], 0, 0, 0);
        OB[0] = __builtin_amdgcn_mfma_f32_16x16x32_bf16(pfB, vf0, OB[0], 0, 0, 0);
        OA[1] = __builtin_amdgcn_mfma_f32_16x16x32_bf16(pfA, vf1, OA[1], 0, 0, 0);
        OB[1] = __builtin_amdgcn_mfma_f32_16x16x32_bf16(pfB, vf1, OB[1], 0, 0, 0);
        OA[2] = __builtin_amdgcn_mfma_f32_16x16x32_bf16(pfA, vf2, OA[2], 0, 0, 0);
        OB[2] = __builtin_amdgcn_mfma_f32_16x16x32_bf16(pfB, vf2, OB[2], 0, 0, 0);
        OA[3] = __builtin_amdgcn_mfma_f32_16x16x32_bf16(pfA, vf3, OA[3], 0, 0, 0);
        OB[3] = __builtin_amdgcn_mfma_f32_16x16x32_bf16(pfB, vf3, OB[3], 0, 0, 0);
        __builtin_amdgcn_s_setprio(0);

        // rotate K pipeline: cur <- next, issue next-next (clamped)
        c1a = n1a; c1b = n1b; c2a = n2a; c2b = n2b;
        const int kbn = (kb0 + 64 < kend) ? kb0 + 64 : kend - 32;
        const __bf16* nk1 = kp1 + (size_t)kbn * DH;
        const __bf16* nk2 = kp2 + (size_t)kbn * DH;
        n1a = *(const bf16x8*)(nk1 + quad * 8);
        n1b = *(const bf16x8*)(nk1 + 32 + quad * 8);
        n2a = *(const bf16x8*)(nk2 + quad * 8);
        n2b = *(const bf16x8*)(nk2 + 32 + quad * 8);
    }

    // reduce denominators across quads (each lane then holds the full sum
    // for query l16 (A) / 16+l16 (B))
    lA += __shfl_xor(lA, 16);
    lA += __shfl_xor(lA, 32);
    lB += __shfl_xor(lB, 16);
    lB += __shfl_xor(lB, 32);

    #pragma unroll
    for (int r = 0; r < 4; ++r) {
        const float invA = 1.0f / __shfl(lA, quad * 4 + r);
        const float invB = 1.0f / __shfl(lB, quad * 4 + r);
        const int ltA = quad * 4 + r;      // tile-local row 0..15
        const int ltB = ltA + 16;          // 16..31
        const int tA = q0 + ltA;
        const int tB = q0 + ltB;
        float* opA = attn_vec + ((size_t)bh * TT + tA) * DH + l16;
        float* opB = attn_vec + ((size_t)bh * TT + tB) * DH + l16;
        #pragma unroll
        for (int nt = 0; nt < 4; ++nt) {
            const float vA = OA[nt][r] * invA;
            const float vB = OB[nt][r] * invB;
            opA[nt * 16] = vA;
            opB[nt * 16] = vB;
            atomicAdd(&smav[ltA][nt * 16 + l16], vA * (1.f / 16.f));
            atomicAdd(&smav[ltB][nt * 16 + l16], vB * (1.f / 16.f));
        }
    }

    __syncthreads();

    // block-cooperative float4 store of the head-mean (each element once)
    if (threadIdx.x < 512) {
        const int row = threadIdx.x >> 4;          // 0..31
        const int d0  = (threadIdx.x & 15) * 4;
        float4 v;
        v.x = smav[row][d0];
        v.y = smav[row][d0 + 1];
        v.z = smav[row][d0 + 2];
        v.w = smav[row][d0 + 3];
        *(float4*)(mav + ((size_t)(b * TT + q0 + row)) * DH + d0) = v;
    }
}

// ---------------------------------------------------------------------------
// Out-proj GEMM (64x64 tile, fp32 A): out[M,1024] = mav[M,64] @ Wo[64,1024]
// ---------------------------------------------------------------------------
__global__ __launch_bounds__(256) void gemm_out(
    const float* __restrict__ A, const float* __restrict__ B,
    float* __restrict__ C, int M, int N, int K)
{
    __shared__ __align__(16) __bf16 sA[64][32];
    __shared__ __align__(16) __bf16 sB[64][32];

    const int tid  = threadIdx.x;
    const int wave = tid >> 6;
    const int lane = tid & 63;
    const int m0 = blockIdx.y * 64;
    const int n0 = blockIdx.x * 64;

    f32x4 acc[4] = {f32x4{0,0,0,0}, f32x4{0,0,0,0}, f32x4{0,0,0,0}, f32x4{0,0,0,0}};

    const int ar = tid >> 2;
    const int ac = (tid & 3) * 8;
    const int bk = tid >> 3;
    const int bc = (tid & 7) * 8;
    const int quad = lane >> 4;
    const int l16  = lane & 15;

    for (int k0 = 0; k0 < K; k0 += 32) {
        const float* ap = A + (size_t)(m0 + ar) * K + k0 + ac;
        float4 a0 = *(const float4*)ap;
        float4 a1 = *(const float4*)(ap + 4);
        {
            bf16x8 av;
            av[0] = (__bf16)a0.x; av[1] = (__bf16)a0.y; av[2] = (__bf16)a0.z; av[3] = (__bf16)a0.w;
            av[4] = (__bf16)a1.x; av[5] = (__bf16)a1.y; av[6] = (__bf16)a1.z; av[7] = (__bf16)a1.w;
            *(bf16x8*)&sA[ar][ac] = av;
        }
        const float* bp = B + (size_t)(k0 + bk) * N + n0 + bc;
        float4 b0 = *(const float4*)bp;
        float4 b1 = *(const float4*)(bp + 4);
        sB[bc + 0][bk] = (__bf16)b0.x;
        sB[bc + 1][bk] = (__bf16)b0.y;
        sB[bc + 2][bk] = (__bf16)b0.z;
        sB[bc + 3][bk] = (__bf16)b0.w;
        sB[bc + 4][bk] = (__bf16)b1.x;
        sB[bc + 5][bk] = (__bf16)b1.y;
        sB[bc + 6][bk] = (__bf16)b1.z;
        sB[bc + 7][bk] = (__bf16)b1.w;
        __syncthreads();

        bf16x8 afrag = *(const bf16x8*)&sA[wave * 16 + l16][quad * 8];
        #pragma unroll
        for (int tn = 0; tn < 4; ++tn) {
            bf16x8 bfrag = *(const bf16x8*)&sB[tn * 16 + l16][quad * 8];
            acc[tn] = __builtin_amdgcn_mfma_f32_16x16x32_bf16(afrag, bfrag, acc[tn], 0, 0, 0);
        }
        __syncthreads();
    }

    #pragma unroll
    for (int tn = 0; tn < 4; ++tn) {
        #pragma unroll
        for (int r = 0; r < 4; ++r) {
            int row = m0 + wave * 16 + quad * 4 + r;
            int col = n0 + tn * 16 + l16;
            C[(size_t)row * N + col] = acc[tn][r];
        }
    }
}

// ---------------------------------------------------------------------------
extern "C" void kernel_launch(void* const* d_in, const int* in_sizes, int n_in,
                              void* d_out, int out_size, void* d_ws, size_t ws_size,
                              hipStream_t stream)
{
    const float* x  = (const float*)d_in[0];
    const float* Wq = (const float*)d_in[1];
    const float* bq = (const float*)d_in[2];
    const float* Wk = (const float*)d_in[3];
    const float* bk = (const float*)d_in[4];
    const float* Wv = (const float*)d_in[5];
    const float* bv = (const float*)d_in[6];
    const float* Wo = (const float*)d_in[7];

    float* out      = (float*)d_out;                       // [32,512,1024]
    float* attn_vec = out + (size_t)MM * HH;               // [32,16,512,64]

    char* ws = (char*)d_ws;
    __bf16* xb  = (__bf16*)ws;                              // [M][1024]    33.5 MB
    __bf16* Wt  = xb + (size_t)MM * HH;                     // [2176][1024]  4.45 MB
    float* bias_cat = (float*)(Wt + (size_t)NCAT * HH);     // 2176 (pad 2304)
    __bf16* Qb  = (__bf16*)(bias_cat + 2304);               // [b,h,t,d]    33.5 MB
    __bf16* Kb  = Qb + (size_t)MM * HH;                     // [b,h,t,d]    33.5 MB
    __bf16* Vt  = Kb + (size_t)MM * HH;                     // [b,d,t]       2.1 MB
    float*  mav = (float*)xb;   // alias: xb dead after gemm_qkv; fully overwritten by attn

    cvt_x<<<MM * HH / (256 * 8), 256, 0, stream>>>(x, xb);
    prep_w<<<dim3(NCAT / 64, HH / 64), 256, 0, stream>>>(Wq, Wk, Wv, bq, bk, bv, Wt, bias_cat);
    gemm_qkv<<<dim3(NCAT / 128, MM / 128), 256, 0, stream>>>(xb, Wt, bias_cat, Qb, Kb, Vt);
    attn_mfma<<<BS * NH, 1024, 0, stream>>>(Qb, Kb, Vt, attn_vec, mav);
    gemm_out<<<dim3(HH / 64, MM / 64), 256, 0, stream>>>(mav, Wo, out, MM, HH, DH);
}

// Round 6
// 359.229 us; speedup vs baseline: 1.2226x; 1.2226x over previous
//
#include <hip/hip_runtime.h>
#include <hip/hip_bf16.h>
#include <math.h>

// Problem constants
#define BS 32
#define TT 512
#define HH 1024
#define NH 16
#define DH 64
#define MM (BS*TT)          // 16384 rows
#define NCAT 2176           // 1024(Q) + 1024(K) + 64(V) + 64(pad)

typedef __attribute__((ext_vector_type(8))) __bf16 bf16x8;
typedef __attribute__((ext_vector_type(4))) float  f32x4;

#define QSCALE 0.18033688011112042f   // dh^-0.5 * log2(e) -> softmax in exp2 domain

// Native 2^x (single v_exp_f32); confirmed R5: halved VALUBusy.
#if __has_builtin(__builtin_amdgcn_exp2f)
#define EXP2F(x) __builtin_amdgcn_exp2f(x)
#else
#define EXP2F(x) __expf((x) * 0.69314718055994531f)
#endif

// async global->LDS, 16B per lane, LDS dest = wave-uniform base + lane*16
__device__ __forceinline__ void gld16(const void* g, void* l) {
    __builtin_amdgcn_global_load_lds(
        (const __attribute__((address_space(1))) unsigned int*)g,
        (__attribute__((address_space(3))) unsigned int*)l,
        16, 0, 0);
}

// ---------------------------------------------------------------------------
// Prep 1: x fp32 -> bf16 (row-major [M][K] unchanged)
// ---------------------------------------------------------------------------
__global__ __launch_bounds__(256) void cvt_x(const float* __restrict__ x,
                                             __bf16* __restrict__ xb)
{
    const size_t i = ((size_t)blockIdx.x * 256 + threadIdx.x) * 8;
    float4 a = *(const float4*)(x + i);
    float4 b = *(const float4*)(x + i + 4);
    bf16x8 v;
    v[0] = (__bf16)a.x; v[1] = (__bf16)a.y; v[2] = (__bf16)a.z; v[3] = (__bf16)a.w;
    v[4] = (__bf16)b.x; v[5] = (__bf16)b.y; v[6] = (__bf16)b.z; v[7] = (__bf16)b.w;
    *(bf16x8*)(xb + i) = v;
}

// ---------------------------------------------------------------------------
// Prep 2: Wt[n][k] bf16 = concat(Wq,Wk,Wv,0)^T; bias_cat[n] fp32.
// ---------------------------------------------------------------------------
__global__ __launch_bounds__(256) void prep_w(
    const float* __restrict__ Wq, const float* __restrict__ Wk,
    const float* __restrict__ Wv, const float* __restrict__ bq_,
    const float* __restrict__ bk_, const float* __restrict__ bv_,
    __bf16* __restrict__ Wt, float* __restrict__ bias_cat)
{
    __shared__ __align__(16) __bf16 tile[64][72];
    const int tid = threadIdx.x;
    const int n0 = blockIdx.x * 64;
    const int k0 = blockIdx.y * 64;

    const int n_l = tid & 63;
    const int k_b = tid >> 6;
    const int n   = n0 + n_l;
    #pragma unroll
    for (int j = 0; j < 16; ++j) {
        const int k_l = j * 4 + k_b;
        const int k   = k0 + k_l;
        float v;
        if (n < 1024)      v = Wq[(size_t)k * 1024 + n];
        else if (n < 2048) v = Wk[(size_t)k * 1024 + (n - 1024)];
        else if (n < 2112) v = Wv[(size_t)k * 64 + (n - 2048)];
        else               v = 0.f;
        tile[n_l][k_l] = (__bf16)v;
    }
    if (blockIdx.y == 0 && tid < 64) {
        const int nn = n0 + tid;
        bias_cat[nn] = (nn < 1024) ? bq_[nn]
                     : (nn < 2048) ? bk_[nn - 1024]
                     : (nn < 2112) ? bv_[nn - 2048] : 0.f;
    }
    __syncthreads();
    const int n_l2 = tid >> 2;
    const int k_l2 = (tid & 3) * 16;
    __bf16* dst = Wt + (size_t)(n0 + n_l2) * 1024 + k0 + k_l2;
    *(bf16x8*)dst       = *(const bf16x8*)&tile[n_l2][k_l2];
    *(bf16x8*)(dst + 8) = *(const bf16x8*)&tile[n_l2][k_l2 + 8];
}

// ---------------------------------------------------------------------------
// Fused QKV GEMM, m97 structure: 128x128 tile, BK=32, global_load_lds w=16.
// Bijective XCD-aware block swizzle (nwg=2176=8*272) for L2 locality.
// ---------------------------------------------------------------------------
__global__ __launch_bounds__(256) void gemm_qkv(
    const __bf16* __restrict__ A, const __bf16* __restrict__ B,
    const float* __restrict__ bias_cat,
    __bf16* __restrict__ Qo, __bf16* __restrict__ Ko,
    __bf16* __restrict__ Vt)
{
    __shared__ __align__(16) __bf16 sA[128 * 32];
    __shared__ __align__(16) __bf16 sB[128 * 32];

    const int tid  = threadIdx.x;
    const int wv   = tid >> 6;
    const int ln   = tid & 63;
    const int quad = ln >> 4;
    const int l16  = ln & 15;

    // XCD swizzle: grid = dim3(17,128) -> 2176 blocks, 2176 % 8 == 0
    const int orig = blockIdx.y * 17 + blockIdx.x;
    const int swz  = (orig & 7) * 272 + (orig >> 3);
    const int m0 = (swz / 17) * 128;
    const int n0 = (swz % 17) * 128;

    const int rw = (wv & 1) * 64;    // wave row quadrant
    const int cw = (wv >> 1) * 64;   // wave col quadrant

    f32x4 acc[4][4];
    #pragma unroll
    for (int i = 0; i < 4; ++i)
        #pragma unroll
        for (int j = 0; j < 4; ++j) acc[i][j] = f32x4{0, 0, 0, 0};

    const int srow = wv * 16 + (ln >> 2);
    const int scol = (ln & 3) * 8;
    const __bf16* ga0 = A + (size_t)(m0 + srow) * 1024 + scol;
    const __bf16* gb0 = B + (size_t)(n0 + srow) * 1024 + scol;
    __bf16* la0 = sA + wv * 512;
    __bf16* lb0 = sB + wv * 512;

    for (int k0 = 0; k0 < 1024; k0 += 32) {
        gld16(ga0 + k0, la0);
        gld16(ga0 + (size_t)64 * 1024 + k0, la0 + 2048);
        gld16(gb0 + k0, lb0);
        gld16(gb0 + (size_t)64 * 1024 + k0, lb0 + 2048);
        __syncthreads();

        bf16x8 af[4], bfr[4];
        #pragma unroll
        for (int mt = 0; mt < 4; ++mt)
            af[mt] = *(const bf16x8*)&sA[(rw + mt * 16 + l16) * 32 + quad * 8];
        #pragma unroll
        for (int nt = 0; nt < 4; ++nt)
            bfr[nt] = *(const bf16x8*)&sB[(cw + nt * 16 + l16) * 32 + quad * 8];
        #pragma unroll
        for (int mt = 0; mt < 4; ++mt)
            #pragma unroll
            for (int nt = 0; nt < 4; ++nt)
                acc[mt][nt] = __builtin_amdgcn_mfma_f32_16x16x32_bf16(af[mt], bfr[nt], acc[mt][nt], 0, 0, 0);
        __syncthreads();
    }

    #pragma unroll
    for (int mt = 0; mt < 4; ++mt) {
        #pragma unroll
        for (int nt = 0; nt < 4; ++nt) {
            const int colb = n0 + cw + nt * 16 + l16;
            if (colb >= 2112) continue;
            const float bias = bias_cat[colb];
            #pragma unroll
            for (int r = 0; r < 4; ++r) {
                const int row = m0 + rw + mt * 16 + quad * 4 + r;
                const int b = row >> 9, t = row & 511;
                float v = acc[mt][nt][r] + bias;
                if (colb < 1024) {
                    const int h = colb >> 6, d = colb & 63;
                    Qo[(((size_t)(b * NH + h) * TT) + t) * DH + d] = (__bf16)(v * QSCALE);
                } else if (colb < 2048) {
                    const int c = colb - 1024;
                    const int h = c >> 6, d = c & 63;
                    Ko[(((size_t)(b * NH + h) * TT) + t) * DH + d] = (__bf16)v;
                } else {
                    const int d = colb - 2048;
                    Vt[((size_t)(b * DH + d)) * TT + t] = (__bf16)v;
                }
            }
        }
    }
}

// ---------------------------------------------------------------------------
// MFMA flash attention, v6: block = ONE HEAD (bh), 16 waves = 16 q-tiles.
// R2-R5 post-mortems: every memory fix worked on counters, time pinned at
// 125-140us -> latency-bound on the per-wave PRIVATE global K gather (each
// wave = different head -> K unshareable). v6 inverts the decomposition so
// K IS shared: stage K (64KB, XOR-swizzled, T21 both-sides) + V (64KB,
// existing verified scheme) in LDS once -> the k-loop is 100% LDS/compute,
// zero global loads. ds_read latency ~120cyc hidden by 4 waves/SIMD.
//  * qt2->wave map {s,7-s,8+s,15-s} per SIMD s: every SIMD gets exactly
//    34 wave-iterations -> intra-block balance; all 512 blocks identical
//    (full causal triangle per head) -> perfect global balance.
//  * head-mean moved to a separate BW-bound reduce_heads kernel (attn_vec
//    is a required output anyway) -> no smav, no LDS atomics, no epilogue
//    barrier here.
//  * no setprio (R5 regression suspect), EXP2F kept (R5-confirmed win).
// LDS 128KB -> 1 block/CU, grid 512 = 2 identical sequential rounds.
// ---------------------------------------------------------------------------
__global__ __launch_bounds__(1024) void attn_mfma(
    const __bf16* __restrict__ Q, const __bf16* __restrict__ K,
    const __bf16* __restrict__ Vt, float* __restrict__ attn_vec)
{
    __shared__ __align__(16) __bf16 sK[512 * 64];   // 64 KB [t][d], 16B groups XOR-swizzled by swzK(t)
    __shared__ __align__(16) __bf16 sV[64][512];    // 64 KB [d][t], 16B groups XOR-swizzled by (d&7)

    const int bh   = blockIdx.x;           // b*NH + h
    const int b    = bh >> 4;
    const int wave = threadIdx.x >> 6;
    const int lane = threadIdx.x & 63;
    const int quad = lane >> 4;
    const int l16  = lane & 15;

    // SIMD-balanced qt2 assignment: SIMD s = wave&3 hosts qt2 {s,7-s,8+s,15-s}
    const int s_ = wave & 3, j_ = wave >> 2;
    const int qt2 = (j_ == 0) ? s_ : (j_ == 1) ? (7 - s_) : (j_ == 2) ? (8 + s_) : (15 - s_);
    const int q0   = qt2 << 5;
    const int kend = q0 + 32;

    const __bf16* Qbh = Q + (size_t)bh * TT * DH;
    const __bf16* Kbh = K + (size_t)bh * TT * DH;
    const __bf16* Vb  = Vt + (size_t)b * DH * TT;

    // ---- stage K: wave w stages row-chunks c = w*4+r (8 rows each).
    // Linear LDS dest; physical 16B-group p=lane&7 of row gets logical group
    // p ^ swzK(row), swzK(row) = (row&3) | (((row>>3)&1)<<2)  [T21 involution]
    #pragma unroll
    for (int r = 0; r < 4; ++r) {
        const int c   = wave * 4 + r;
        const int row = c * 8 + (lane >> 3);
        const int p   = lane & 7;
        const int swz = (row & 3) | (((row >> 3) & 1) << 2);
        gld16(Kbh + (size_t)row * DH + ((p ^ swz) * 8), sK + (size_t)c * 512);
    }
    // ---- stage V: wave w stages rows w, w+16, w+32, w+48 (row&7 = w&7).
    const int svw = wave & 7;
    #pragma unroll
    for (int r = 0; r < 4; ++r) {
        const int row = wave + r * 16;
        gld16(Vb + (size_t)row * TT + ((lane ^ svw) * 8), &sV[row][0]);
    }

    // Q fragments for this wave's 32-query tile (global, once)
    const bf16x8 qA_lo = *(const bf16x8*)(Qbh + (size_t)(q0 + l16) * DH + quad * 8);
    const bf16x8 qA_hi = *(const bf16x8*)(Qbh + (size_t)(q0 + l16) * DH + 32 + quad * 8);
    const bf16x8 qB_lo = *(const bf16x8*)(Qbh + (size_t)(q0 + 16 + l16) * DH + quad * 8);
    const bf16x8 qB_hi = *(const bf16x8*)(Qbh + (size_t)(q0 + 16 + l16) * DH + 32 + quad * 8);

    // permuted K row: sigma1(l16) = (l16>>2)*8 + (l16&3); sigma2 = +4.
    // swzK is constant per lane for BOTH pointers across all kb0 (kb0%32==0):
    // row&3 = l16&3, (row>>3)&1 = (l16>>2)&1.
    const int perm = ((l16 >> 2) << 3) + (l16 & 3);
    const int swzl = (l16 & 3) | (((l16 >> 2) & 1) << 2);
    const __bf16* k1lo = sK + (size_t)perm * DH       + (( quad      ^ swzl) * 8);
    const __bf16* k1hi = sK + (size_t)perm * DH       + (((quad | 4) ^ swzl) * 8);
    const __bf16* k2lo = sK + (size_t)(perm + 4) * DH + (( quad      ^ swzl) * 8);
    const __bf16* k2hi = sK + (size_t)(perm + 4) * DH + (((quad | 4) ^ swzl) * 8);

    const int sx = l16 & 7;   // V read swizzle

    f32x4 OA[4] = {f32x4{0,0,0,0}, f32x4{0,0,0,0}, f32x4{0,0,0,0}, f32x4{0,0,0,0}};
    f32x4 OB[4] = {f32x4{0,0,0,0}, f32x4{0,0,0,0}, f32x4{0,0,0,0}, f32x4{0,0,0,0}};
    float lA = 0.f, lB = 0.f;     // per-lane partial denominators

    __syncthreads();   // K+V staged (compiler drains vmcnt before s_barrier)

    for (int kb0 = 0; kb0 < kend; kb0 += 32) {
        const int ko = kb0 * DH;   // element offset of this K block
        bf16x8 c1a = *(const bf16x8*)(k1lo + ko);
        bf16x8 c1b = *(const bf16x8*)(k1hi + ko);
        bf16x8 c2a = *(const bf16x8*)(k2lo + ko);
        bf16x8 c2b = *(const bf16x8*)(k2hi + ko);

        // V fragments: logical group (kb0>>3)+quad -> physical ^sx
        const int vg = (((kb0 >> 3) + quad) ^ sx) * 8;
        bf16x8 vf0 = *(const bf16x8*)&sV[l16][vg];
        bf16x8 vf1 = *(const bf16x8*)&sV[16 + l16][vg];
        bf16x8 vf2 = *(const bf16x8*)&sV[32 + l16][vg];
        bf16x8 vf3 = *(const bf16x8*)&sV[48 + l16][vg];

        f32x4 s1A = __builtin_amdgcn_mfma_f32_16x16x32_bf16(c1a, qA_lo, f32x4{0,0,0,0}, 0, 0, 0);
        s1A       = __builtin_amdgcn_mfma_f32_16x16x32_bf16(c1b, qA_hi, s1A, 0, 0, 0);
        f32x4 s2A = __builtin_amdgcn_mfma_f32_16x16x32_bf16(c2a, qA_lo, f32x4{0,0,0,0}, 0, 0, 0);
        s2A       = __builtin_amdgcn_mfma_f32_16x16x32_bf16(c2b, qA_hi, s2A, 0, 0, 0);
        f32x4 s1B = __builtin_amdgcn_mfma_f32_16x16x32_bf16(c1a, qB_lo, f32x4{0,0,0,0}, 0, 0, 0);
        s1B       = __builtin_amdgcn_mfma_f32_16x16x32_bf16(c1b, qB_hi, s1B, 0, 0, 0);
        f32x4 s2B = __builtin_amdgcn_mfma_f32_16x16x32_bf16(c2a, qB_lo, f32x4{0,0,0,0}, 0, 0, 0);
        s2B       = __builtin_amdgcn_mfma_f32_16x16x32_bf16(c2b, qB_hi, s2B, 0, 0, 0);

        if (kb0 == q0) {   // only the diagonal block needs masking
            const int qqA = q0 + l16, qqB = q0 + 16 + l16;
            #pragma unroll
            for (int r = 0; r < 4; ++r) {
                const int key1 = kb0 + quad * 8 + r;
                const int key2 = key1 + 4;
                if (key1 > qqA) s1A[r] = -INFINITY;
                if (key2 > qqA) s2A[r] = -INFINITY;
                if (key1 > qqB) s1B[r] = -INFINITY;
                if (key2 > qqB) s2B[r] = -INFINITY;
            }
        }

        // p = exp2(s) via native v_exp_f32; accumulate per-lane denominator
        bf16x8 pfA, pfB;
        float psA0 = 0.f, psA1 = 0.f, psB0 = 0.f, psB1 = 0.f;
        #pragma unroll
        for (int r = 0; r < 4; ++r) {
            float pa0 = EXP2F(s1A[r]);
            float pa1 = EXP2F(s2A[r]);
            float pb0 = EXP2F(s1B[r]);
            float pb1 = EXP2F(s2B[r]);
            psA0 += pa0; psA1 += pa1;
            psB0 += pb0; psB1 += pb1;
            pfA[r]     = (__bf16)pa0;
            pfA[4 + r] = (__bf16)pa1;
            pfB[r]     = (__bf16)pb0;
            pfB[4 + r] = (__bf16)pb1;
        }
        lA += psA0 + psA1;
        lB += psB0 + psB1;

        OA[0] = __builtin_amdgcn_mfma_f32_16x16x32_bf16(pfA, vf0, OA[0], 0, 0, 0);
        OB[0] = __builtin_amdgcn_mfma_f32_16x16x32_bf16(pfB, vf0, OB[0], 0, 0, 0);
        OA[1] = __builtin_amdgcn_mfma_f32_16x16x32_bf16(pfA, vf1, OA[1], 0, 0, 0);
        OB[1] = __builtin_amdgcn_mfma_f32_16x16x32_bf16(pfB, vf1, OB[1], 0, 0, 0);
        OA[2] = __builtin_amdgcn_mfma_f32_16x16x32_bf16(pfA, vf2, OA[2], 0, 0, 0);
        OB[2] = __builtin_amdgcn_mfma_f32_16x16x32_bf16(pfB, vf2, OB[2], 0, 0, 0);
        OA[3] = __builtin_amdgcn_mfma_f32_16x16x32_bf16(pfA, vf3, OA[3], 0, 0, 0);
        OB[3] = __builtin_amdgcn_mfma_f32_16x16x32_bf16(pfB, vf3, OB[3], 0, 0, 0);
    }

    // reduce denominators across quads (each lane then holds the full sum
    // for query l16 (A) / 16+l16 (B))
    lA += __shfl_xor(lA, 16);
    lA += __shfl_xor(lA, 32);
    lB += __shfl_xor(lB, 16);
    lB += __shfl_xor(lB, 32);

    #pragma unroll
    for (int r = 0; r < 4; ++r) {
        const float invA = 1.0f / __shfl(lA, quad * 4 + r);
        const float invB = 1.0f / __shfl(lB, quad * 4 + r);
        const int tA = q0 + quad * 4 + r;
        const int tB = tA + 16;
        float* opA = attn_vec + ((size_t)bh * TT + tA) * DH + l16;
        float* opB = attn_vec + ((size_t)bh * TT + tB) * DH + l16;
        #pragma unroll
        for (int nt = 0; nt < 4; ++nt) {
            opA[nt * 16] = OA[nt][r] * invA;
            opB[nt * 16] = OB[nt][r] * invB;
        }
    }
}

// ---------------------------------------------------------------------------
// Head-mean: mav[b,t,d] = (1/16) sum_h attn_vec[b,h,t,d].  BW-bound ~71MB.
// ---------------------------------------------------------------------------
__global__ __launch_bounds__(256) void reduce_heads(
    const float* __restrict__ av, float* __restrict__ mav)
{
    const size_t idx = (size_t)blockIdx.x * 256 + threadIdx.x;  // over MM*DH/4
    const int    d4  = (int)(idx & 15);            // DH/4 = 16 float4 per row
    const size_t bt  = idx >> 4;                   // b*TT + t
    const int    b   = (int)(bt >> 9);
    const int    t   = (int)(bt & 511);
    const float4* p = (const float4*)av + (((size_t)b * NH * TT) + t) * 16 + d4;
    float4 a = p[0];
    #pragma unroll
    for (int h = 1; h < NH; ++h) {
        float4 v = p[(size_t)h * TT * 16];
        a.x += v.x; a.y += v.y; a.z += v.z; a.w += v.w;
    }
    float4 o;
    o.x = a.x * (1.f / 16.f); o.y = a.y * (1.f / 16.f);
    o.z = a.z * (1.f / 16.f); o.w = a.w * (1.f / 16.f);
    ((float4*)mav)[idx] = o;
}

// ---------------------------------------------------------------------------
// Out-proj GEMM (64x64 tile, fp32 A): out[M,1024] = mav[M,64] @ Wo[64,1024]
// ---------------------------------------------------------------------------
__global__ __launch_bounds__(256) void gemm_out(
    const float* __restrict__ A, const float* __restrict__ B,
    float* __restrict__ C, int M, int N, int K)
{
    __shared__ __align__(16) __bf16 sA[64][32];
    __shared__ __align__(16) __bf16 sB[64][32];

    const int tid  = threadIdx.x;
    const int wave = tid >> 6;
    const int lane = tid & 63;
    const int m0 = blockIdx.y * 64;
    const int n0 = blockIdx.x * 64;

    f32x4 acc[4] = {f32x4{0,0,0,0}, f32x4{0,0,0,0}, f32x4{0,0,0,0}, f32x4{0,0,0,0}};

    const int ar = tid >> 2;
    const int ac = (tid & 3) * 8;
    const int bk = tid >> 3;
    const int bc = (tid & 7) * 8;
    const int quad = lane >> 4;
    const int l16  = lane & 15;

    for (int k0 = 0; k0 < K; k0 += 32) {
        const float* ap = A + (size_t)(m0 + ar) * K + k0 + ac;
        float4 a0 = *(const float4*)ap;
        float4 a1 = *(const float4*)(ap + 4);
        {
            bf16x8 av;
            av[0] = (__bf16)a0.x; av[1] = (__bf16)a0.y; av[2] = (__bf16)a0.z; av[3] = (__bf16)a0.w;
            av[4] = (__bf16)a1.x; av[5] = (__bf16)a1.y; av[6] = (__bf16)a1.z; av[7] = (__bf16)a1.w;
            *(bf16x8*)&sA[ar][ac] = av;
        }
        const float* bp = B + (size_t)(k0 + bk) * N + n0 + bc;
        float4 b0 = *(const float4*)bp;
        float4 b1 = *(const float4*)(bp + 4);
        sB[bc + 0][bk] = (__bf16)b0.x;
        sB[bc + 1][bk] = (__bf16)b0.y;
        sB[bc + 2][bk] = (__bf16)b0.z;
        sB[bc + 3][bk] = (__bf16)b0.w;
        sB[bc + 4][bk] = (__bf16)b1.x;
        sB[bc + 5][bk] = (__bf16)b1.y;
        sB[bc + 6][bk] = (__bf16)b1.z;
        sB[bc + 7][bk] = (__bf16)b1.w;
        __syncthreads();

        bf16x8 afrag = *(const bf16x8*)&sA[wave * 16 + l16][quad * 8];
        #pragma unroll
        for (int tn = 0; tn < 4; ++tn) {
            bf16x8 bfrag = *(const bf16x8*)&sB[tn * 16 + l16][quad * 8];
            acc[tn] = __builtin_amdgcn_mfma_f32_16x16x32_bf16(afrag, bfrag, acc[tn], 0, 0, 0);
        }
        __syncthreads();
    }

    #pragma unroll
    for (int tn = 0; tn < 4; ++tn) {
        #pragma unroll
        for (int r = 0; r < 4; ++r) {
            int row = m0 + wave * 16 + quad * 4 + r;
            int col = n0 + tn * 16 + l16;
            C[(size_t)row * N + col] = acc[tn][r];
        }
    }
}

// ---------------------------------------------------------------------------
extern "C" void kernel_launch(void* const* d_in, const int* in_sizes, int n_in,
                              void* d_out, int out_size, void* d_ws, size_t ws_size,
                              hipStream_t stream)
{
    const float* x  = (const float*)d_in[0];
    const float* Wq = (const float*)d_in[1];
    const float* bq = (const float*)d_in[2];
    const float* Wk = (const float*)d_in[3];
    const float* bk = (const float*)d_in[4];
    const float* Wv = (const float*)d_in[5];
    const float* bv = (const float*)d_in[6];
    const float* Wo = (const float*)d_in[7];

    float* out      = (float*)d_out;                       // [32,512,1024]
    float* attn_vec = out + (size_t)MM * HH;               // [32,16,512,64]

    char* ws = (char*)d_ws;
    __bf16* xb  = (__bf16*)ws;                              // [M][1024]    33.5 MB
    __bf16* Wt  = xb + (size_t)MM * HH;                     // [2176][1024]  4.45 MB
    float* bias_cat = (float*)(Wt + (size_t)NCAT * HH);     // 2176 (pad 2304)
    __bf16* Qb  = (__bf16*)(bias_cat + 2304);               // [b,h,t,d]    33.5 MB
    __bf16* Kb  = Qb + (size_t)MM * HH;                     // [b,h,t,d]    33.5 MB
    __bf16* Vt  = Kb + (size_t)MM * HH;                     // [b,d,t]       2.1 MB
    float*  mav = (float*)xb;   // alias: xb dead after gemm_qkv; written by reduce_heads

    cvt_x<<<MM * HH / (256 * 8), 256, 0, stream>>>(x, xb);
    prep_w<<<dim3(NCAT / 64, HH / 64), 256, 0, stream>>>(Wq, Wk, Wv, bq, bk, bv, Wt, bias_cat);
    gemm_qkv<<<dim3(NCAT / 128, MM / 128), 256, 0, stream>>>(xb, Wt, bias_cat, Qb, Kb, Vt);
    attn_mfma<<<BS * NH, 1024, 0, stream>>>(Qb, Kb, Vt, attn_vec);
    reduce_heads<<<(MM * DH / 4) / 256, 256, 0, stream>>>(attn_vec, mav);
    gemm_out<<<dim3(HH / 64, MM / 64), 256, 0, stream>>>(mav, Wo, out, MM, HH, DH);
}